// Round 14
// baseline (503.980 us; speedup 1.0000x reference)
//
#include <hip/hip_runtime.h>
#include <hip/hip_bf16.h>

typedef __attribute__((ext_vector_type(8))) __bf16 bf16x8;
typedef __attribute__((ext_vector_type(4))) float f32x4;

__device__ __forceinline__ unsigned short f2bf(float f) {
    unsigned int u = __float_as_uint(f);
    u += 0x7fff + ((u >> 16) & 1);   // round-to-nearest-even
    return (unsigned short)(u >> 16);
}

__device__ __forceinline__ void gload16(const void* g, void* l) {
    __builtin_amdgcn_global_load_lds(
        (const __attribute__((address_space(1))) void*)g,
        (__attribute__((address_space(3))) void*)l, 16, 0, 0);
}

#define ZOFFB (31040 * 512)   // byte offset of the zero row in every activation buffer

// 125 row-tiles of 256 over the 6 stacked feature maps (31040 rows total)
__device__ __forceinline__ void tile256(int rt, int& rb, int& dim, int& row0) {
    if (rt < 91)       { rb = 0;     dim = 38; row0 = rt * 256; }
    else if (rt < 114) { rb = 23104; dim = 19; row0 = (rt - 91) * 256; }
    else if (rt < 121) { rb = 28880; dim = 10; row0 = (rt - 114) * 256; }
    else if (rt < 123) { rb = 30480; dim = 5;  row0 = (rt - 121) * 256; }
    else if (rt < 124) { rb = 30880; dim = 3;  row0 = (rt - 123) * 256; }
    else               { rb = 31024; dim = 1;  row0 = 0; }
    row0 += rb;
}

// 247 row-tiles of 128 (used by conv_final)
__device__ __forceinline__ void tile128(int rt, int& rb, int& dim, int& row0, int& aoff) {
    if (rt < 181)      { rb = 0;     dim = 38; row0 = rt * 128;         aoff = 0;     }
    else if (rt < 227) { rb = 23104; dim = 19; row0 = (rt - 181) * 128; aoff = 8664;  }
    else if (rt < 240) { rb = 28880; dim = 10; row0 = (rt - 227) * 128; aoff = 10830; }
    else if (rt < 244) { rb = 30480; dim = 5;  row0 = (rt - 240) * 128; aoff = 11430; }
    else if (rt < 246) { rb = 30880; dim = 3;  row0 = (rt - 244) * 128; aoff = 11580; }
    else               { rb = 31024; dim = 1;  row0 = (rt - 246) * 128; aoff = 11634; }
    row0 += rb;
}

// ---------------------------------------------------------------------------
// Weight transform, read-coalesced: one block per output row (co), 256 thr (ci).
// ---------------------------------------------------------------------------
struct WT { const float* src[10]; };
__global__ __launch_bounds__(256) void wtrans_all(WT wt, unsigned short* __restrict__ Wb,
                                                  unsigned short* __restrict__ WF) {
    int cr = blockIdx.x;
    int ci = threadIdx.x;
    const float* src;
    unsigned short* dst;
    int co, Cout;
    if (cr < 2048) {
        int slot = cr >> 8; co = cr & 255;
        src = wt.src[slot];
        dst = Wb + (size_t)slot * 589824 + (size_t)co * 2304;
        Cout = 256;
    } else {
        int r = cr - 2048;
        int slot = r >> 6; co = r & 63;
        src = wt.src[8 + slot];
        dst = WF + (size_t)slot * 147456 + (size_t)co * 2304;
        Cout = slot ? 54 : 24;
    }
    float v[9];
    if (co < Cout) {
        const float* s = src + (size_t)(co * 256 + ci) * 9;
#pragma unroll
        for (int t = 0; t < 9; ++t) v[t] = s[t];
    } else {
#pragma unroll
        for (int t = 0; t < 9; ++t) v[t] = 0.0f;
    }
#pragma unroll
    for (int t = 0; t < 9; ++t) dst[t * 256 + ci] = f2bf(v[t]);
}

// ---------------------------------------------------------------------------
// Fused feature transform: 6 maps NCHW fp32 -> [row][256] bf16.
// Extra tail blocks zero the halo row of each activation buffer.
// ---------------------------------------------------------------------------
struct FT { const float* src[6]; unsigned short* halo[4]; int nh; };
__global__ void ftrans_all(FT ft, unsigned short* __restrict__ X0) {
    int idx = blockIdx.x * 256 + threadIdx.x;
    if (idx >= 993280) {
        int idx2 = idx - 993280;           // [0, 1024)
        int buf = idx2 >> 8, off = idx2 & 255;
        if (buf < ft.nh) ft.halo[buf][off] = 0;
        return;
    }
    int row = idx >> 5;
    int c8  = (idx & 31) << 3;
    int m, rb, dim;
    if (row < 23104)      { m = 0; rb = 0;     dim = 38; }
    else if (row < 28880) { m = 1; rb = 23104; dim = 19; }
    else if (row < 30480) { m = 2; rb = 28880; dim = 10; }
    else if (row < 30880) { m = 3; rb = 30480; dim = 5;  }
    else if (row < 31024) { m = 4; rb = 30880; dim = 3;  }
    else                  { m = 5; rb = 31024; dim = 1;  }
    int HW = dim * dim;
    int rel = row - rb;
    int b = rel / HW;
    int hw = rel - b * HW;
    const float* s = ft.src[m] + (size_t)(b * 256 + c8) * HW + hw;
    union { unsigned short u[8]; uint4 v; } tmp;
#pragma unroll
    for (int j = 0; j < 8; ++j) tmp.u[j] = f2bf(s[(size_t)j * HW]);
    *reinterpret_cast<uint4*>(X0 + ((size_t)row << 8) + c8) = tmp.v;
}

// ---------------------------------------------------------------------------
// conv_gemm: 3x3 conv C256->C256 (+bias+ReLU), both heads via blockIdx.y.
// 256x256 tile, 512 thr = 8 waves (2M x 4N), 128x64 per wave.
// A: BK=32, 4-deep LDS ring (64 KiB), gload_lds staged t+3, counted vmcnt(8),
//    one barrier/step, compiler-scheduled ds_reads+MFMAs.
// B: DIRECT global->register (weights are L2-hot; frag = 16 contiguous bytes),
//    double-buffered one step ahead; backend inserts precise counted waits.
// ---------------------------------------------------------------------------
struct GArgs {
    const unsigned short* X[2];
    const unsigned short* W[2];
    const float* B[2];
    unsigned short* Y[2];
};

__global__ __launch_bounds__(512, 2) void conv_gemm(GArgs ga) {
    __shared__ unsigned char As[65536];   // 4 slots x [256 rows][32ch] bf16

    const int hz = blockIdx.y;
    const unsigned char* __restrict__ Xb = (const unsigned char*)ga.X[hz];
    const unsigned char* __restrict__ Wt = (const unsigned char*)ga.W[hz];
    const float* __restrict__ bias = ga.B[hz];
    unsigned short* __restrict__ Y = ga.Y[hz];

    int rb, dim, row0;
    tile256(blockIdx.x, rb, dim, row0);
    const int HWm = dim * dim;
    const int rowEnd = rb + 16 * HWm;

    const int tid = threadIdx.x;
    const int lane = tid & 63, wid = tid >> 6;
    const int lr = lane & 15, lg = lane >> 4;
    const int wm = wid >> 2, wn = wid & 3;

    // ---- A staging geometry: each thread sources 16B quarters of rows sr0, sr0+128
    const int sr0 = tid >> 2;
    const int xsw = (((tid & 3) ^ ((sr0 >> 1) & 3)) << 4);   // XOR-swizzled quarter
    const unsigned char* Zr = Xb + ZOFFB + xsw;

    int gg[2], ay[2], ax[2];
    bool av[2];
#pragma unroll
    for (int it = 0; it < 2; ++it) {
        int g = row0 + sr0 + it * 128;
        bool v = g < rowEnd;
        int rel = v ? (g - rb) : 0;
        int b = rel / HWm;
        int hw = rel - b * HWm;
        int y = hw / dim;
        gg[it] = g; ay[it] = y; ax[it] = hw - y * dim; av[it] = v;
    }

    auto tapA = [&](int tap, const unsigned char*& p0, const unsigned char*& p1) {
        int q3 = tap / 3;
        int dy = q3 - 1, dx = tap - q3 * 3 - 1;
        int ddd = dy * dim + dx;
        bool v0 = av[0] && ((unsigned)(ay[0] + dy) < (unsigned)dim) && ((unsigned)(ax[0] + dx) < (unsigned)dim);
        bool v1 = av[1] && ((unsigned)(ay[1] + dy) < (unsigned)dim) && ((unsigned)(ax[1] + dx) < (unsigned)dim);
        p0 = v0 ? Xb + (size_t)(gg[0] + ddd) * 512 + xsw : Zr;
        p1 = v1 ? Xb + (size_t)(gg[1] + ddd) * 512 + xsw : Zr;
    };

    // ---- B direct-load base: col = wn*64 + j*16 + lr, bytes [tap*512 + kc*64 + lg*16]
    const unsigned char* bpt = Wt + (size_t)(wn * 64 + lr) * 4608 + lg * 16;
    // j stride = 16 cols * 4608 B = 73728

    // ---- A fragment read offsets (swizzle folds to lr-only term)
    const int fswz = ((lg ^ ((lr >> 1) & 3)) << 4);
    const int aRd = (wm * 128 + lr) * 64 + fswz;
    const int dSt = wid * 1024;

    f32x4 acc[8][4];
#pragma unroll
    for (int i = 0; i < 8; ++i)
#pragma unroll
        for (int j = 0; j < 4; ++j) acc[i][j] = (f32x4){0.f, 0.f, 0.f, 0.f};

    bf16x8 bR[2][4];

    // ---- prologue: stage A K-tiles 0,1,2 (tap 0); load B(0)
    const unsigned char *aC0, *aC1, *aN0, *aN1;
    tapA(0, aC0, aC1);
#pragma unroll
    for (int kt = 0; kt < 3; ++kt) {
        gload16(aC0 + kt * 64, As + kt * 16384 + dSt);
        gload16(aC1 + kt * 64, As + kt * 16384 + 8192 + dSt);
    }
#pragma unroll
    for (int j = 0; j < 4; ++j)
        bR[0][j] = *(const bf16x8*)(bpt + (size_t)j * 73728);

    // ---- main loop: 9 taps x 8 K-tiles of 32 channels (t = tap*8+kc)
#pragma unroll 1
    for (int tap = 0; tap < 9; ++tap) {
        if (tap < 8) tapA(tap + 1, aN0, aN1);
        else { aN0 = Zr; aN1 = Zr; }

#pragma unroll
        for (int kc = 0; kc < 8; ++kc) {
            const int bufc = kc & 3;          // A slot holding K-tile t
            const int bufs = (kc + 3) & 3;    // A slot being staged (t+3)
            const int pc = kc & 1;            // B reg set for this step
            const int pn = pc ^ 1;            // B reg set being loaded (t+1)

            // counted cross-wave sync: A-stage(t-3) writers of slot bufc complete
            asm volatile("s_waitcnt vmcnt(8)" ::: "memory");
            __builtin_amdgcn_s_barrier();
            asm volatile("" ::: "memory");    // no memory op crosses the barrier

            // stage A K-tile t+3
            {
                const unsigned char *sa0, *sa1;
                if (kc < 5) { sa0 = aC0 + (kc + 3) * 64; sa1 = aC1 + (kc + 3) * 64; }
                else        { sa0 = aN0 + (kc - 5) * 64; sa1 = aN1 + (kc - 5) * 64; }
                gload16(sa0, As + bufs * 16384 + dSt);
                gload16(sa1, As + bufs * 16384 + 8192 + dSt);
            }

            // load B(t+1) into the other reg set (backend inserts counted wait)
            {
                const int tn = (tap * 8 + kc + 1) % 72;     // compile-time per (tap,kc)
                const int boff = (tn >> 3) * 512 + (tn & 7) * 64;
#pragma unroll
                for (int j = 0; j < 4; ++j)
                    bR[pn][j] = *(const bf16x8*)(bpt + (size_t)j * 73728 + boff);
            }

            // A fragments + MFMA: compiler-scheduled (fine-grained lgkmcnt)
            const unsigned char* ab = As + bufc * 16384;
            bf16x8 rA[8];
#pragma unroll
            for (int i = 0; i < 8; ++i) rA[i] = *(const bf16x8*)(ab + aRd + i * 1024);
#pragma unroll
            for (int i = 0; i < 8; ++i)
#pragma unroll
                for (int j = 0; j < 4; ++j)
                    acc[i][j] = __builtin_amdgcn_mfma_f32_16x16x32_bf16(rA[i], bR[pc][j], acc[i][j], 0, 0, 0);
        }
        aC0 = aN0; aC1 = aN1;
    }

    // ---- epilogue: bias + ReLU + bf16 store
    float bj[4];
#pragma unroll
    for (int j = 0; j < 4; ++j) bj[j] = bias[wn * 64 + j * 16 + lr];
#pragma unroll
    for (int i = 0; i < 8; ++i) {
        int rbase = row0 + wm * 128 + i * 16 + lg * 4;
#pragma unroll
        for (int rr = 0; rr < 4; ++rr) {
            int orow = rbase + rr;
            if (orow < rowEnd) {
                size_t yb = (size_t)orow * 256 + wn * 64 + lr;
#pragma unroll
                for (int j = 0; j < 4; ++j) {
                    float v = acc[i][j][rr] + bj[j];
                    Y[yb + j * 16] = f2bf(fmaxf(v, 0.f));
                }
            }
        }
    }
}

// ---------------------------------------------------------------------------
// conv_final: last conv (Cout pad 64) + bias + anchor-layout scatter, both heads.
// 128x64 tile, 4 waves stacked in M (32x64 each). r13 schedule (ring-4,
// counted vmcnt(6), one barrier/step, compiler-scheduled).
// ---------------------------------------------------------------------------
struct FArgs {
    const unsigned short* X[2];
    const unsigned short* W[2];
    const float* B[2];
    float* out;
    int hbase;
};

__global__ __launch_bounds__(256) void conv_final(FArgs fa) {
    __shared__ unsigned char As[32768];   // 4 slots x 8KB: [128 rows][64B]
    __shared__ unsigned char Bs[16384];   // 4 slots x 4KB: [64 cols][64B]

    const int zi = blockIdx.z;
    const int hz = zi + fa.hbase;
    const unsigned char* Xb = (const unsigned char*)fa.X[zi];
    const unsigned char* Wt = (const unsigned char*)fa.W[zi];
    const float* bias = fa.B[zi];
    float* out = fa.out;

    int rb, dim, row0, aoff;
    tile128(blockIdx.x, rb, dim, row0, aoff);
    const int HWm = dim * dim;
    const int rowEnd = rb + 16 * HWm;

    const int tid = threadIdx.x;
    const int lane = tid & 63, wid = tid >> 6;
    const int lr = lane & 15, lg = lane >> 4;

    const int swz16 = (((lane & 3) ^ ((lane >> 3) & 3)) << 4);
    const int srow = wid * 16 + (lane >> 2);
    const unsigned char* Zr = Xb + ZOFFB + swz16;

    int ay[2], ax[2], arel[2];
    bool av0[2];
#pragma unroll
    for (int it = 0; it < 2; ++it) {
        int r = row0 + it * 64 + srow;
        bool v = r < rowEnd;
        int rel = v ? (r - rb) : 0;
        int b = rel / HWm;
        int hw = rel - b * HWm;
        int y = hw / dim;
        ay[it] = y; ax[it] = hw - y * dim; arel[it] = rel; av0[it] = v;
    }

    const unsigned char* bB = Wt + (size_t)srow * 4608 + swz16;

    const int fsw = ((lg ^ ((lr >> 1) & 3)) << 4);
    const int aRd = (wid * 32 + lr) * 64 + fsw;   // + i*1024 + slot*8192
    const int bRd = lr * 64 + fsw;                // + j*1024 + slot*4096
    const int dA0 = wid * 1024;

    f32x4 acc[2][4];
#pragma unroll
    for (int i = 0; i < 2; ++i)
#pragma unroll
        for (int j = 0; j < 4; ++j) acc[i][j] = (f32x4){0.f, 0.f, 0.f, 0.f};

    auto tapPtr = [&](int tap, const unsigned char** aP) {
        int q3 = tap / 3;
        int dy = q3 - 1, dx = tap - q3 * 3 - 1;
#pragma unroll
        for (int it = 0; it < 2; ++it) {
            bool v = av0[it] && ((unsigned)(ay[it] + dy) < (unsigned)dim)
                             && ((unsigned)(ax[it] + dx) < (unsigned)dim);
            int off = v ? (rb + arel[it] + dy * dim + dx) * 512 : ZOFFB;
            aP[it] = Xb + off + swz16;
        }
    };

    // ---- prologue: stage K-tiles 0,1,2 (tap 0)
    const unsigned char* aP[2];
    const unsigned char* aPn[2];
    tapPtr(0, aP);
#pragma unroll
    for (int kt = 0; kt < 3; ++kt) {
        gload16(aP[0] + kt * 64, As + kt * 8192 + dA0);
        gload16(aP[1] + kt * 64, As + kt * 8192 + 4096 + dA0);
        gload16(bB + kt * 64, Bs + kt * 4096 + dA0);
    }

    // ---- main loop: 9 taps x 8 K-tiles of 32 channels (t = tap*8+kin)
#pragma unroll 1
    for (int tap = 0; tap < 9; ++tap) {
        if (tap < 8) tapPtr(tap + 1, aPn);
        else { aPn[0] = Zr; aPn[1] = Zr; }
        const unsigned char* bP = bB + tap * 512;

#pragma unroll
        for (int kin = 0; kin < 8; ++kin) {
            const int sc = kin & 3;           // slot holding K-tile t
            const int ss = (kin + 3) & 3;     // slot being staged (t+3)

            asm volatile("s_waitcnt vmcnt(6)" ::: "memory");   // slot sc landed
            __builtin_amdgcn_s_barrier();
            asm volatile("" ::: "memory");

            // stage K-tile t+3 (dummy Zr loads past the end keep the count uniform)
            {
                const unsigned char *sa0, *sa1, *sb;
                if (tap == 8 && kin >= 5) { sa0 = Zr; sa1 = Zr; sb = Zr; }
                else if (kin < 5) {
                    sa0 = aP[0] + (kin + 3) * 64; sa1 = aP[1] + (kin + 3) * 64;
                    sb = bP + (kin + 3) * 64;
                } else {
                    sa0 = aPn[0] + (kin - 5) * 64; sa1 = aPn[1] + (kin - 5) * 64;
                    sb = bP + 512 + (kin - 5) * 64;
                }
                gload16(sa0, As + ss * 8192 + dA0);
                gload16(sa1, As + ss * 8192 + 4096 + dA0);
                gload16(sb, Bs + ss * 4096 + dA0);
            }

            // fragments + MFMA: compiler-scheduled
            const unsigned char* ab = As + sc * 8192;
            const unsigned char* bb = Bs + sc * 4096;
            bf16x8 af[2], bg[4];
#pragma unroll
            for (int j = 0; j < 4; ++j) bg[j] = *(const bf16x8*)(bb + bRd + j * 1024);
#pragma unroll
            for (int i = 0; i < 2; ++i) af[i] = *(const bf16x8*)(ab + aRd + i * 1024);
#pragma unroll
            for (int i = 0; i < 2; ++i)
#pragma unroll
                for (int j = 0; j < 4; ++j)
                    acc[i][j] = __builtin_amdgcn_mfma_f32_16x16x32_bf16(af[i], bg[j], acc[i][j], 0, 0, 0);
        }
        aP[0] = aPn[0]; aP[1] = aPn[1];
    }

    const int Cout = hz ? 54 : 24;
#pragma unroll
    for (int i = 0; i < 2; ++i) {
        int rbase = row0 + wid * 32 + i * 16 + lg * 4;
#pragma unroll
        for (int r = 0; r < 4; ++r) {
            int orow = rbase + r;
            if (orow < rowEnd) {
                int rel = orow - rb;
                int b = rel / HWm;
                int hw = rel - b * HWm;
#pragma unroll
                for (int j = 0; j < 4; ++j) {
                    int oc = j * 16 + lr;
                    if (oc < Cout) {
                        int q = oc / 6;
                        int s = oc - q * 6;
                        int anchor = aoff + s * HWm + hw;
                        float v = acc[i][j][r] + bias[oc];
                        if (hz)
                            out[744960 + (size_t)b * 104760 + (size_t)q * 11640 + anchor] = v;
                        else
                            out[(size_t)b * 46560 + (size_t)q * 11640 + anchor] = v;
                    }
                }
            }
        }
    }
}

// ---------------------------------------------------------------------------
extern "C" void kernel_launch(void* const* d_in, const int* in_sizes, int n_in,
                              void* d_out, int out_size, void* d_ws, size_t ws_size,
                              hipStream_t stream) {
    (void)in_sizes; (void)n_in; (void)out_size;

    const float* rw[5]  = {(const float*)d_in[6],  (const float*)d_in[8],
                           (const float*)d_in[10], (const float*)d_in[12],
                           (const float*)d_in[14]};
    const float* rbv[5] = {(const float*)d_in[7],  (const float*)d_in[9],
                           (const float*)d_in[11], (const float*)d_in[13],
                           (const float*)d_in[15]};
    const float* cw[5]  = {(const float*)d_in[16], (const float*)d_in[18],
                           (const float*)d_in[20], (const float*)d_in[22],
                           (const float*)d_in[24]};
    const float* cbv[5] = {(const float*)d_in[17], (const float*)d_in[19],
                           (const float*)d_in[21], (const float*)d_in[23],
                           (const float*)d_in[25]};

    const size_t ACTB = 31041ull * 512;
    const size_t WMAT = 589824;
    const size_t WBYTES = 8 * WMAT * 2;
    const size_t WFBYTES = 2 * 147456 * 2;
    const size_t needF = 4 * ACTB + WBYTES + WFBYTES;
    const size_t needS = 3 * ACTB + WBYTES + WFBYTES;

    unsigned char* ws = (unsigned char*)d_ws;
    bool fused = (ws_size >= needF);
    if (!fused && ws_size < needS) return;

    int nact = fused ? 4 : 3;
    unsigned short* act[4];
    for (int i = 0; i < nact; ++i) act[i] = (unsigned short*)(ws + (size_t)i * ACTB);
    unsigned short* Wb = (unsigned short*)(ws + (size_t)nact * ACTB);
    unsigned short* WF = (unsigned short*)(ws + (size_t)nact * ACTB + WBYTES);

    WT wt;
    for (int l = 0; l < 4; ++l) { wt.src[l] = rw[l]; wt.src[4 + l] = cw[l]; }
    wt.src[8] = rw[4]; wt.src[9] = cw[4];
    wtrans_all<<<2176, 256, 0, stream>>>(wt, Wb, WF);

    FT ft;
    for (int i = 0; i < 6; ++i) ft.src[i] = (const float*)d_in[i];
    for (int i = 0; i < 4; ++i)
        ft.halo[i] = (unsigned short*)((unsigned char*)act[i < nact ? i : 0] + ZOFFB);
    ft.nh = nact;
    ftrans_all<<<3884, 256, 0, stream>>>(ft, act[0]);

    const unsigned short* Wr[5], *Wc[5];
    for (int l = 0; l < 4; ++l) {
        Wr[l] = Wb + (size_t)l * WMAT;
        Wc[l] = Wb + (size_t)(4 + l) * WMAT;
    }
    Wr[4] = WF; Wc[4] = WF + 147456;

    if (fused) {
        unsigned short* X0 = act[0];
        unsigned short* P = act[1];
        unsigned short* Q = act[2];
        unsigned short* R = act[3];
        GArgs l1 = {{X0, X0}, {Wr[0], Wc[0]}, {rbv[0], cbv[0]}, {P, Q}};
        GArgs l2 = {{P,  Q},  {Wr[1], Wc[1]}, {rbv[1], cbv[1]}, {X0, R}};
        GArgs l3 = {{X0, R},  {Wr[2], Wc[2]}, {rbv[2], cbv[2]}, {P, Q}};
        GArgs l4 = {{P,  Q},  {Wr[3], Wc[3]}, {rbv[3], cbv[3]}, {X0, R}};
        conv_gemm<<<dim3(125, 2), 512, 0, stream>>>(l1);
        conv_gemm<<<dim3(125, 2), 512, 0, stream>>>(l2);
        conv_gemm<<<dim3(125, 2), 512, 0, stream>>>(l3);
        conv_gemm<<<dim3(125, 2), 512, 0, stream>>>(l4);
        FArgs lf = {{X0, R}, {Wr[4], Wc[4]}, {rbv[4], cbv[4]}, (float*)d_out, 0};
        conv_final<<<dim3(247, 1, 2), 256, 0, stream>>>(lf);
    } else {
        unsigned short* X0 = act[0];
        unsigned short* A1 = act[1];
        unsigned short* A2 = act[2];
        for (int h = 0; h < 2; ++h) {
            const unsigned short* const* W = h ? Wc : Wr;
            const float* const* bs = h ? cbv : rbv;
            GArgs l1 = {{X0, X0}, {W[0], W[0]}, {bs[0], bs[0]}, {A1, A1}};
            GArgs l2 = {{A1, A1}, {W[1], W[1]}, {bs[1], bs[1]}, {A2, A2}};
            GArgs l3 = {{A2, A2}, {W[2], W[2]}, {bs[2], bs[2]}, {A1, A1}};
            GArgs l4 = {{A1, A1}, {W[3], W[3]}, {bs[3], bs[3]}, {A2, A2}};
            conv_gemm<<<dim3(125, 1), 512, 0, stream>>>(l1);
            conv_gemm<<<dim3(125, 1), 512, 0, stream>>>(l2);
            conv_gemm<<<dim3(125, 1), 512, 0, stream>>>(l3);
            conv_gemm<<<dim3(125, 1), 512, 0, stream>>>(l4);
            FArgs lf = {{A2, A2}, {W[4], W[4]}, {bs[4], bs[4]}, (float*)d_out, h};
            conv_final<<<dim3(247, 1, 1), 256, 0, stream>>>(lf);
        }
    }
}

// Round 15
// 382.904 us; speedup vs baseline: 1.3162x; 1.3162x over previous
//
#include <hip/hip_runtime.h>
#include <hip/hip_bf16.h>

typedef __attribute__((ext_vector_type(8))) __bf16 bf16x8;
typedef __attribute__((ext_vector_type(4))) float f32x4;

__device__ __forceinline__ unsigned short f2bf(float f) {
    unsigned int u = __float_as_uint(f);
    u += 0x7fff + ((u >> 16) & 1);   // round-to-nearest-even
    return (unsigned short)(u >> 16);
}

__device__ __forceinline__ void gload16(const void* g, void* l) {
    __builtin_amdgcn_global_load_lds(
        (const __attribute__((address_space(1))) void*)g,
        (__attribute__((address_space(3))) void*)l, 16, 0, 0);
}

#define ZOFFB (31040 * 512)   // byte offset of the zero row in every activation buffer

// 125 row-tiles of 256 over the 6 stacked feature maps (31040 rows total)
__device__ __forceinline__ void tile256(int rt, int& rb, int& dim, int& row0) {
    if (rt < 91)       { rb = 0;     dim = 38; row0 = rt * 256; }
    else if (rt < 114) { rb = 23104; dim = 19; row0 = (rt - 91) * 256; }
    else if (rt < 121) { rb = 28880; dim = 10; row0 = (rt - 114) * 256; }
    else if (rt < 123) { rb = 30480; dim = 5;  row0 = (rt - 121) * 256; }
    else if (rt < 124) { rb = 30880; dim = 3;  row0 = (rt - 123) * 256; }
    else               { rb = 31024; dim = 1;  row0 = 0; }
    row0 += rb;
}

// 247 row-tiles of 128 (used by conv_final)
__device__ __forceinline__ void tile128(int rt, int& rb, int& dim, int& row0, int& aoff) {
    if (rt < 181)      { rb = 0;     dim = 38; row0 = rt * 128;         aoff = 0;     }
    else if (rt < 227) { rb = 23104; dim = 19; row0 = (rt - 181) * 128; aoff = 8664;  }
    else if (rt < 240) { rb = 28880; dim = 10; row0 = (rt - 227) * 128; aoff = 10830; }
    else if (rt < 244) { rb = 30480; dim = 5;  row0 = (rt - 240) * 128; aoff = 11430; }
    else if (rt < 246) { rb = 30880; dim = 3;  row0 = (rt - 244) * 128; aoff = 11580; }
    else               { rb = 31024; dim = 1;  row0 = (rt - 246) * 128; aoff = 11634; }
    row0 += rb;
}

// ---------------------------------------------------------------------------
// Weight transform, read-coalesced: one block per output row (co), 256 thr (ci).
// ---------------------------------------------------------------------------
struct WT { const float* src[10]; };
__global__ __launch_bounds__(256) void wtrans_all(WT wt, unsigned short* __restrict__ Wb,
                                                  unsigned short* __restrict__ WF) {
    int cr = blockIdx.x;
    int ci = threadIdx.x;
    const float* src;
    unsigned short* dst;
    int co, Cout;
    if (cr < 2048) {
        int slot = cr >> 8; co = cr & 255;
        src = wt.src[slot];
        dst = Wb + (size_t)slot * 589824 + (size_t)co * 2304;
        Cout = 256;
    } else {
        int r = cr - 2048;
        int slot = r >> 6; co = r & 63;
        src = wt.src[8 + slot];
        dst = WF + (size_t)slot * 147456 + (size_t)co * 2304;
        Cout = slot ? 54 : 24;
    }
    float v[9];
    if (co < Cout) {
        const float* s = src + (size_t)(co * 256 + ci) * 9;
#pragma unroll
        for (int t = 0; t < 9; ++t) v[t] = s[t];
    } else {
#pragma unroll
        for (int t = 0; t < 9; ++t) v[t] = 0.0f;
    }
#pragma unroll
    for (int t = 0; t < 9; ++t) dst[t * 256 + ci] = f2bf(v[t]);
}

// ---------------------------------------------------------------------------
// Fused feature transform: 6 maps NCHW fp32 -> [row][256] bf16.
// Extra tail blocks zero the halo row of each activation buffer.
// ---------------------------------------------------------------------------
struct FT { const float* src[6]; unsigned short* halo[4]; int nh; };
__global__ void ftrans_all(FT ft, unsigned short* __restrict__ X0) {
    int idx = blockIdx.x * 256 + threadIdx.x;
    if (idx >= 993280) {
        int idx2 = idx - 993280;           // [0, 1024)
        int buf = idx2 >> 8, off = idx2 & 255;
        if (buf < ft.nh) ft.halo[buf][off] = 0;
        return;
    }
    int row = idx >> 5;
    int c8  = (idx & 31) << 3;
    int m, rb, dim;
    if (row < 23104)      { m = 0; rb = 0;     dim = 38; }
    else if (row < 28880) { m = 1; rb = 23104; dim = 19; }
    else if (row < 30480) { m = 2; rb = 28880; dim = 10; }
    else if (row < 30880) { m = 3; rb = 30480; dim = 5;  }
    else if (row < 31024) { m = 4; rb = 30880; dim = 3;  }
    else                  { m = 5; rb = 31024; dim = 1;  }
    int HW = dim * dim;
    int rel = row - rb;
    int b = rel / HW;
    int hw = rel - b * HW;
    const float* s = ft.src[m] + (size_t)(b * 256 + c8) * HW + hw;
    union { unsigned short u[8]; uint4 v; } tmp;
#pragma unroll
    for (int j = 0; j < 8; ++j) tmp.u[j] = f2bf(s[(size_t)j * HW]);
    *reinterpret_cast<uint4*>(X0 + ((size_t)row << 8) + c8) = tmp.v;
}

// ---------------------------------------------------------------------------
// conv_gemm: 3x3 conv C256->C256 (+bias+ReLU), both heads via blockIdx.y.
// 256x256 tile, 512 thr = 8 waves (2M x 4N), 128x64 per wave.
// BK=32, 4-deep LDS ring. TWO K-tiles per barrier block:
//   vmcnt(0) [stage(t),stage(t+1) done - issued a full block earlier, ~free]
//   -> barrier -> stage(t+2),(t+3) -> reads+MFMAs for tiles t, t+1
// Barriers/waits halved vs per-step schedule; ds_reads+MFMAs compiler-scheduled.
// ---------------------------------------------------------------------------
struct GArgs {
    const unsigned short* X[2];
    const unsigned short* W[2];
    const float* B[2];
    unsigned short* Y[2];
};

__global__ __launch_bounds__(512, 2) void conv_gemm(GArgs ga) {
    __shared__ unsigned char As[65536];   // 4 slots x [256 rows][32ch] bf16
    __shared__ unsigned char Bs[65536];   // 4 slots x [256 cols][32ch]

    const int hz = blockIdx.y;
    const unsigned char* __restrict__ Xb = (const unsigned char*)ga.X[hz];
    const unsigned char* __restrict__ Wt = (const unsigned char*)ga.W[hz];
    const float* __restrict__ bias = ga.B[hz];
    unsigned short* __restrict__ Y = ga.Y[hz];

    int rb, dim, row0;
    tile256(blockIdx.x, rb, dim, row0);
    const int HWm = dim * dim;
    const int rowEnd = rb + 16 * HWm;

    const int tid = threadIdx.x;
    const int lane = tid & 63, wid = tid >> 6;
    const int lr = lane & 15, lg = lane >> 4;
    const int wm = wid >> 2, wn = wid & 3;

    // ---- staging geometry: each thread sources 16B quarters of rows sr0, sr0+128
    const int sr0 = tid >> 2;
    const int xsw = (((tid & 3) ^ ((sr0 >> 1) & 3)) << 4);   // XOR-swizzled quarter
    const unsigned char* Zr = Xb + ZOFFB + xsw;

    int gg[2], ay[2], ax[2];
    bool av[2];
#pragma unroll
    for (int it = 0; it < 2; ++it) {
        int g = row0 + sr0 + it * 128;
        bool v = g < rowEnd;
        int rel = v ? (g - rb) : 0;
        int b = rel / HWm;
        int hw = rel - b * HWm;
        int y = hw / dim;
        gg[it] = g; ay[it] = y; ax[it] = hw - y * dim; av[it] = v;
    }

    const unsigned char* bsrc0 = Wt + (size_t)sr0 * 4608 + xsw;
    const unsigned char* bsrc1 = Wt + (size_t)(sr0 + 128) * 4608 + xsw;

    auto tapA = [&](int tap, const unsigned char*& p0, const unsigned char*& p1) {
        int q3 = tap / 3;
        int dy = q3 - 1, dx = tap - q3 * 3 - 1;
        int ddd = dy * dim + dx;
        bool v0 = av[0] && ((unsigned)(ay[0] + dy) < (unsigned)dim) && ((unsigned)(ax[0] + dx) < (unsigned)dim);
        bool v1 = av[1] && ((unsigned)(ay[1] + dy) < (unsigned)dim) && ((unsigned)(ax[1] + dx) < (unsigned)dim);
        p0 = v0 ? Xb + (size_t)(gg[0] + ddd) * 512 + xsw : Zr;
        p1 = v1 ? Xb + (size_t)(gg[1] + ddd) * 512 + xsw : Zr;
    };

    // ---- fragment read offsets (swizzle folds to lr-only term)
    const int fswz = ((lg ^ ((lr >> 1) & 3)) << 4);
    const int aRd = (wm * 128 + lr) * 64 + fswz;
    const int bRd = (wn * 64 + lr) * 64 + fswz;
    const int dSt = wid * 1024;

    f32x4 acc[8][4];
#pragma unroll
    for (int i = 0; i < 8; ++i)
#pragma unroll
        for (int j = 0; j < 4; ++j) acc[i][j] = (f32x4){0.f, 0.f, 0.f, 0.f};

    // ---- prologue: stage K-tiles 0,1 (tap 0)
    const unsigned char *aC0, *aC1, *aN0, *aN1;
    tapA(0, aC0, aC1);
#pragma unroll
    for (int kt = 0; kt < 2; ++kt) {
        gload16(aC0 + kt * 64, As + kt * 16384 + dSt);
        gload16(aC1 + kt * 64, As + kt * 16384 + 8192 + dSt);
        gload16(bsrc0 + kt * 64, Bs + kt * 16384 + dSt);
        gload16(bsrc1 + kt * 64, Bs + kt * 16384 + 8192 + dSt);
    }

    // ---- main loop: 9 taps x 4 K-tile PAIRS (t = tap*8 + kc, kc = 2*kc2)
#pragma unroll 1
    for (int tap = 0; tap < 9; ++tap) {
        if (tap < 8) tapA(tap + 1, aN0, aN1);
        else { aN0 = Zr; aN1 = Zr; }
        const unsigned char* bT0 = bsrc0 + tap * 512;
        const unsigned char* bT1 = bsrc1 + tap * 512;
        const unsigned char* bN0 = bT0 + 512;   // tap+1 (never dereferenced when tap==8)
        const unsigned char* bN1 = bT1 + 512;

#pragma unroll
        for (int kc2 = 0; kc2 < 4; ++kc2) {
            const int kc = kc2 * 2;

            // all own staging loads complete -> barrier -> slots t,t+1 valid block-wide
            asm volatile("s_waitcnt vmcnt(0)" ::: "memory");
            __builtin_amdgcn_s_barrier();
            asm volatile("" ::: "memory");    // no memory op crosses the barrier

            // stage K-tiles t+2, t+3
#pragma unroll
            for (int d = 2; d <= 3; ++d) {
                const int k = kc + d;              // 2..9
                const int sl = k & 3;
                const unsigned char *sa0, *sa1, *sb0, *sb1;
                if (tap == 8 && k >= 8) { sa0 = Zr; sa1 = Zr; sb0 = Zr; sb1 = Zr; }
                else if (k < 8) {
                    sa0 = aC0 + k * 64; sa1 = aC1 + k * 64;
                    sb0 = bT0 + k * 64; sb1 = bT1 + k * 64;
                } else {
                    sa0 = aN0 + (k - 8) * 64; sa1 = aN1 + (k - 8) * 64;
                    sb0 = bN0 + (k - 8) * 64; sb1 = bN1 + (k - 8) * 64;
                }
                gload16(sa0, As + sl * 16384 + dSt);
                gload16(sa1, As + sl * 16384 + 8192 + dSt);
                gload16(sb0, Bs + sl * 16384 + dSt);
                gload16(sb1, Bs + sl * 16384 + 8192 + dSt);
            }

            // two K-tiles of fragments + MFMA: compiler-scheduled (fine lgkmcnt)
#pragma unroll
            for (int d = 0; d < 2; ++d) {
                const int sl = (kc + d) & 3;
                const unsigned char* ab = As + sl * 16384;
                const unsigned char* bb = Bs + sl * 16384;
                bf16x8 rA[8], rB[4];
#pragma unroll
                for (int j = 0; j < 4; ++j) rB[j] = *(const bf16x8*)(bb + bRd + j * 1024);
#pragma unroll
                for (int i = 0; i < 8; ++i) rA[i] = *(const bf16x8*)(ab + aRd + i * 1024);
#pragma unroll
                for (int i = 0; i < 8; ++i)
#pragma unroll
                    for (int j = 0; j < 4; ++j)
                        acc[i][j] = __builtin_amdgcn_mfma_f32_16x16x32_bf16(rA[i], rB[j], acc[i][j], 0, 0, 0);
            }
        }
        aC0 = aN0; aC1 = aN1;
    }

    // ---- epilogue: bias + ReLU + bf16 store
    float bj[4];
#pragma unroll
    for (int j = 0; j < 4; ++j) bj[j] = bias[wn * 64 + j * 16 + lr];
#pragma unroll
    for (int i = 0; i < 8; ++i) {
        int rbase = row0 + wm * 128 + i * 16 + lg * 4;
#pragma unroll
        for (int rr = 0; rr < 4; ++rr) {
            int orow = rbase + rr;
            if (orow < rowEnd) {
                size_t yb = (size_t)orow * 256 + wn * 64 + lr;
#pragma unroll
                for (int j = 0; j < 4; ++j) {
                    float v = acc[i][j][rr] + bj[j];
                    Y[yb + j * 16] = f2bf(fmaxf(v, 0.f));
                }
            }
        }
    }
}

// ---------------------------------------------------------------------------
// conv_final: last conv (Cout pad 64) + bias + anchor-layout scatter, both heads.
// 128x64 tile, 4 waves stacked in M (32x64 each). r13 schedule (ring-4,
// counted vmcnt(6), one barrier/step, compiler-scheduled).
// ---------------------------------------------------------------------------
struct FArgs {
    const unsigned short* X[2];
    const unsigned short* W[2];
    const float* B[2];
    float* out;
    int hbase;
};

__global__ __launch_bounds__(256) void conv_final(FArgs fa) {
    __shared__ unsigned char As[32768];   // 4 slots x 8KB: [128 rows][64B]
    __shared__ unsigned char Bs[16384];   // 4 slots x 4KB: [64 cols][64B]

    const int zi = blockIdx.z;
    const int hz = zi + fa.hbase;
    const unsigned char* Xb = (const unsigned char*)fa.X[zi];
    const unsigned char* Wt = (const unsigned char*)fa.W[zi];
    const float* bias = fa.B[zi];
    float* out = fa.out;

    int rb, dim, row0, aoff;
    tile128(blockIdx.x, rb, dim, row0, aoff);
    const int HWm = dim * dim;
    const int rowEnd = rb + 16 * HWm;

    const int tid = threadIdx.x;
    const int lane = tid & 63, wid = tid >> 6;
    const int lr = lane & 15, lg = lane >> 4;

    const int swz16 = (((lane & 3) ^ ((lane >> 3) & 3)) << 4);
    const int srow = wid * 16 + (lane >> 2);
    const unsigned char* Zr = Xb + ZOFFB + swz16;

    int ay[2], ax[2], arel[2];
    bool av0[2];
#pragma unroll
    for (int it = 0; it < 2; ++it) {
        int r = row0 + it * 64 + srow;
        bool v = r < rowEnd;
        int rel = v ? (r - rb) : 0;
        int b = rel / HWm;
        int hw = rel - b * HWm;
        int y = hw / dim;
        ay[it] = y; ax[it] = hw - y * dim; arel[it] = rel; av0[it] = v;
    }

    const unsigned char* bB = Wt + (size_t)srow * 4608 + swz16;

    const int fsw = ((lg ^ ((lr >> 1) & 3)) << 4);
    const int aRd = (wid * 32 + lr) * 64 + fsw;   // + i*1024 + slot*8192
    const int bRd = lr * 64 + fsw;                // + j*1024 + slot*4096
    const int dA0 = wid * 1024;

    f32x4 acc[2][4];
#pragma unroll
    for (int i = 0; i < 2; ++i)
#pragma unroll
        for (int j = 0; j < 4; ++j) acc[i][j] = (f32x4){0.f, 0.f, 0.f, 0.f};

    auto tapPtr = [&](int tap, const unsigned char** aP) {
        int q3 = tap / 3;
        int dy = q3 - 1, dx = tap - q3 * 3 - 1;
#pragma unroll
        for (int it = 0; it < 2; ++it) {
            bool v = av0[it] && ((unsigned)(ay[it] + dy) < (unsigned)dim)
                             && ((unsigned)(ax[it] + dx) < (unsigned)dim);
            int off = v ? (rb + arel[it] + dy * dim + dx) * 512 : ZOFFB;
            aP[it] = Xb + off + swz16;
        }
    };

    // ---- prologue: stage K-tiles 0,1,2 (tap 0)
    const unsigned char* aP[2];
    const unsigned char* aPn[2];
    tapPtr(0, aP);
#pragma unroll
    for (int kt = 0; kt < 3; ++kt) {
        gload16(aP[0] + kt * 64, As + kt * 8192 + dA0);
        gload16(aP[1] + kt * 64, As + kt * 8192 + 4096 + dA0);
        gload16(bB + kt * 64, Bs + kt * 4096 + dA0);
    }

    // ---- main loop: 9 taps x 8 K-tiles of 32 channels (t = tap*8+kin)
#pragma unroll 1
    for (int tap = 0; tap < 9; ++tap) {
        if (tap < 8) tapPtr(tap + 1, aPn);
        else { aPn[0] = Zr; aPn[1] = Zr; }
        const unsigned char* bP = bB + tap * 512;

#pragma unroll
        for (int kin = 0; kin < 8; ++kin) {
            const int sc = kin & 3;           // slot holding K-tile t
            const int ss = (kin + 3) & 3;     // slot being staged (t+3)

            asm volatile("s_waitcnt vmcnt(6)" ::: "memory");   // slot sc landed
            __builtin_amdgcn_s_barrier();
            asm volatile("" ::: "memory");

            // stage K-tile t+3 (dummy Zr loads past the end keep the count uniform)
            {
                const unsigned char *sa0, *sa1, *sb;
                if (tap == 8 && kin >= 5) { sa0 = Zr; sa1 = Zr; sb = Zr; }
                else if (kin < 5) {
                    sa0 = aP[0] + (kin + 3) * 64; sa1 = aP[1] + (kin + 3) * 64;
                    sb = bP + (kin + 3) * 64;
                } else {
                    sa0 = aPn[0] + (kin - 5) * 64; sa1 = aPn[1] + (kin - 5) * 64;
                    sb = bP + 512 + (kin - 5) * 64;
                }
                gload16(sa0, As + ss * 8192 + dA0);
                gload16(sa1, As + ss * 8192 + 4096 + dA0);
                gload16(sb, Bs + ss * 4096 + dA0);
            }

            // fragments + MFMA: compiler-scheduled
            const unsigned char* ab = As + sc * 8192;
            const unsigned char* bb = Bs + sc * 4096;
            bf16x8 af[2], bg[4];
#pragma unroll
            for (int j = 0; j < 4; ++j) bg[j] = *(const bf16x8*)(bb + bRd + j * 1024);
#pragma unroll
            for (int i = 0; i < 2; ++i) af[i] = *(const bf16x8*)(ab + aRd + i * 1024);
#pragma unroll
            for (int i = 0; i < 2; ++i)
#pragma unroll
                for (int j = 0; j < 4; ++j)
                    acc[i][j] = __builtin_amdgcn_mfma_f32_16x16x32_bf16(af[i], bg[j], acc[i][j], 0, 0, 0);
        }
        aP[0] = aPn[0]; aP[1] = aPn[1];
    }

    const int Cout = hz ? 54 : 24;
#pragma unroll
    for (int i = 0; i < 2; ++i) {
        int rbase = row0 + wid * 32 + i * 16 + lg * 4;
#pragma unroll
        for (int r = 0; r < 4; ++r) {
            int orow = rbase + r;
            if (orow < rowEnd) {
                int rel = orow - rb;
                int b = rel / HWm;
                int hw = rel - b * HWm;
#pragma unroll
                for (int j = 0; j < 4; ++j) {
                    int oc = j * 16 + lr;
                    if (oc < Cout) {
                        int q = oc / 6;
                        int s = oc - q * 6;
                        int anchor = aoff + s * HWm + hw;
                        float v = acc[i][j][r] + bias[oc];
                        if (hz)
                            out[744960 + (size_t)b * 104760 + (size_t)q * 11640 + anchor] = v;
                        else
                            out[(size_t)b * 46560 + (size_t)q * 11640 + anchor] = v;
                    }
                }
            }
        }
    }
}

// ---------------------------------------------------------------------------
extern "C" void kernel_launch(void* const* d_in, const int* in_sizes, int n_in,
                              void* d_out, int out_size, void* d_ws, size_t ws_size,
                              hipStream_t stream) {
    (void)in_sizes; (void)n_in; (void)out_size;

    const float* rw[5]  = {(const float*)d_in[6],  (const float*)d_in[8],
                           (const float*)d_in[10], (const float*)d_in[12],
                           (const float*)d_in[14]};
    const float* rbv[5] = {(const float*)d_in[7],  (const float*)d_in[9],
                           (const float*)d_in[11], (const float*)d_in[13],
                           (const float*)d_in[15]};
    const float* cw[5]  = {(const float*)d_in[16], (const float*)d_in[18],
                           (const float*)d_in[20], (const float*)d_in[22],
                           (const float*)d_in[24]};
    const float* cbv[5] = {(const float*)d_in[17], (const float*)d_in[19],
                           (const float*)d_in[21], (const float*)d_in[23],
                           (const float*)d_in[25]};

    const size_t ACTB = 31041ull * 512;
    const size_t WMAT = 589824;
    const size_t WBYTES = 8 * WMAT * 2;
    const size_t WFBYTES = 2 * 147456 * 2;
    const size_t needF = 4 * ACTB + WBYTES + WFBYTES;
    const size_t needS = 3 * ACTB + WBYTES + WFBYTES;

    unsigned char* ws = (unsigned char*)d_ws;
    bool fused = (ws_size >= needF);
    if (!fused && ws_size < needS) return;

    int nact = fused ? 4 : 3;
    unsigned short* act[4];
    for (int i = 0; i < nact; ++i) act[i] = (unsigned short*)(ws + (size_t)i * ACTB);
    unsigned short* Wb = (unsigned short*)(ws + (size_t)nact * ACTB);
    unsigned short* WF = (unsigned short*)(ws + (size_t)nact * ACTB + WBYTES);

    WT wt;
    for (int l = 0; l < 4; ++l) { wt.src[l] = rw[l]; wt.src[4 + l] = cw[l]; }
    wt.src[8] = rw[4]; wt.src[9] = cw[4];
    wtrans_all<<<2176, 256, 0, stream>>>(wt, Wb, WF);

    FT ft;
    for (int i = 0; i < 6; ++i) ft.src[i] = (const float*)d_in[i];
    for (int i = 0; i < 4; ++i)
        ft.halo[i] = (unsigned short*)((unsigned char*)act[i < nact ? i : 0] + ZOFFB);
    ft.nh = nact;
    ftrans_all<<<3884, 256, 0, stream>>>(ft, act[0]);

    const unsigned short* Wr[5], *Wc[5];
    for (int l = 0; l < 4; ++l) {
        Wr[l] = Wb + (size_t)l * WMAT;
        Wc[l] = Wb + (size_t)(4 + l) * WMAT;
    }
    Wr[4] = WF; Wc[4] = WF + 147456;

    if (fused) {
        unsigned short* X0 = act[0];
        unsigned short* P = act[1];
        unsigned short* Q = act[2];
        unsigned short* R = act[3];
        GArgs l1 = {{X0, X0}, {Wr[0], Wc[0]}, {rbv[0], cbv[0]}, {P, Q}};
        GArgs l2 = {{P,  Q},  {Wr[1], Wc[1]}, {rbv[1], cbv[1]}, {X0, R}};
        GArgs l3 = {{X0, R},  {Wr[2], Wc[2]}, {rbv[2], cbv[2]}, {P, Q}};
        GArgs l4 = {{P,  Q},  {Wr[3], Wc[3]}, {rbv[3], cbv[3]}, {X0, R}};
        conv_gemm<<<dim3(125, 2), 512, 0, stream>>>(l1);
        conv_gemm<<<dim3(125, 2), 512, 0, stream>>>(l2);
        conv_gemm<<<dim3(125, 2), 512, 0, stream>>>(l3);
        conv_gemm<<<dim3(125, 2), 512, 0, stream>>>(l4);
        FArgs lf = {{X0, R}, {Wr[4], Wc[4]}, {rbv[4], cbv[4]}, (float*)d_out, 0};
        conv_final<<<dim3(247, 1, 2), 256, 0, stream>>>(lf);
    } else {
        unsigned short* X0 = act[0];
        unsigned short* A1 = act[1];
        unsigned short* A2 = act[2];
        for (int h = 0; h < 2; ++h) {
            const unsigned short* const* W = h ? Wc : Wr;
            const float* const* bs = h ? cbv : rbv;
            GArgs l1 = {{X0, X0}, {W[0], W[0]}, {bs[0], bs[0]}, {A1, A1}};
            GArgs l2 = {{A1, A1}, {W[1], W[1]}, {bs[1], bs[1]}, {A2, A2}};
            GArgs l3 = {{A2, A2}, {W[2], W[2]}, {bs[2], bs[2]}, {A1, A1}};
            GArgs l4 = {{A1, A1}, {W[3], W[3]}, {bs[3], bs[3]}, {A2, A2}};
            conv_gemm<<<dim3(125, 1), 512, 0, stream>>>(l1);
            conv_gemm<<<dim3(125, 1), 512, 0, stream>>>(l2);
            conv_gemm<<<dim3(125, 1), 512, 0, stream>>>(l3);
            conv_gemm<<<dim3(125, 1), 512, 0, stream>>>(l4);
            FArgs lf = {{A2, A2}, {W[4], W[4]}, {bs[4], bs[4]}, (float*)d_out, h};
            conv_final<<<dim3(247, 1, 1), 256, 0, stream>>>(lf);
        }
    }
}

// Round 16
// 373.209 us; speedup vs baseline: 1.3504x; 1.0260x over previous
//
#include <hip/hip_runtime.h>
#include <hip/hip_bf16.h>

typedef __attribute__((ext_vector_type(8))) __bf16 bf16x8;
typedef __attribute__((ext_vector_type(4))) float f32x4;

__device__ __forceinline__ unsigned short f2bf(float f) {
    unsigned int u = __float_as_uint(f);
    u += 0x7fff + ((u >> 16) & 1);   // round-to-nearest-even
    return (unsigned short)(u >> 16);
}

__device__ __forceinline__ void gload16(const void* g, void* l) {
    __builtin_amdgcn_global_load_lds(
        (const __attribute__((address_space(1))) void*)g,
        (__attribute__((address_space(3))) void*)l, 16, 0, 0);
}

#define ZOFFB (31040 * 512)   // byte offset of the zero row in every activation buffer

// 125 row-tiles of 256 over the 6 stacked feature maps (31040 rows total)
__device__ __forceinline__ void tile256(int rt, int& rb, int& dim, int& row0) {
    if (rt < 91)       { rb = 0;     dim = 38; row0 = rt * 256; }
    else if (rt < 114) { rb = 23104; dim = 19; row0 = (rt - 91) * 256; }
    else if (rt < 121) { rb = 28880; dim = 10; row0 = (rt - 114) * 256; }
    else if (rt < 123) { rb = 30480; dim = 5;  row0 = (rt - 121) * 256; }
    else if (rt < 124) { rb = 30880; dim = 3;  row0 = (rt - 123) * 256; }
    else               { rb = 31024; dim = 1;  row0 = 0; }
    row0 += rb;
}

// 247 row-tiles of 128 (used by conv_final)
__device__ __forceinline__ void tile128(int rt, int& rb, int& dim, int& row0, int& aoff) {
    if (rt < 181)      { rb = 0;     dim = 38; row0 = rt * 128;         aoff = 0;     }
    else if (rt < 227) { rb = 23104; dim = 19; row0 = (rt - 181) * 128; aoff = 8664;  }
    else if (rt < 240) { rb = 28880; dim = 10; row0 = (rt - 227) * 128; aoff = 10830; }
    else if (rt < 244) { rb = 30480; dim = 5;  row0 = (rt - 240) * 128; aoff = 11430; }
    else if (rt < 246) { rb = 30880; dim = 3;  row0 = (rt - 244) * 128; aoff = 11580; }
    else               { rb = 31024; dim = 1;  row0 = (rt - 246) * 128; aoff = 11634; }
    row0 += rb;
}

// ---------------------------------------------------------------------------
// Weight transform, read-coalesced: one block per output row (co), 256 thr (ci).
// ---------------------------------------------------------------------------
struct WT { const float* src[10]; };
__global__ __launch_bounds__(256) void wtrans_all(WT wt, unsigned short* __restrict__ Wb,
                                                  unsigned short* __restrict__ WF) {
    int cr = blockIdx.x;
    int ci = threadIdx.x;
    const float* src;
    unsigned short* dst;
    int co, Cout;
    if (cr < 2048) {
        int slot = cr >> 8; co = cr & 255;
        src = wt.src[slot];
        dst = Wb + (size_t)slot * 589824 + (size_t)co * 2304;
        Cout = 256;
    } else {
        int r = cr - 2048;
        int slot = r >> 6; co = r & 63;
        src = wt.src[8 + slot];
        dst = WF + (size_t)slot * 147456 + (size_t)co * 2304;
        Cout = slot ? 54 : 24;
    }
    float v[9];
    if (co < Cout) {
        const float* s = src + (size_t)(co * 256 + ci) * 9;
#pragma unroll
        for (int t = 0; t < 9; ++t) v[t] = s[t];
    } else {
#pragma unroll
        for (int t = 0; t < 9; ++t) v[t] = 0.0f;
    }
#pragma unroll
    for (int t = 0; t < 9; ++t) dst[t * 256 + ci] = f2bf(v[t]);
}

// ---------------------------------------------------------------------------
// Fused feature transform: 6 maps NCHW fp32 -> [row][256] bf16.
// Extra tail blocks zero the halo row of each activation buffer.
// ---------------------------------------------------------------------------
struct FT { const float* src[6]; unsigned short* halo[4]; int nh; };
__global__ void ftrans_all(FT ft, unsigned short* __restrict__ X0) {
    int idx = blockIdx.x * 256 + threadIdx.x;
    if (idx >= 993280) {
        int idx2 = idx - 993280;           // [0, 1024)
        int buf = idx2 >> 8, off = idx2 & 255;
        if (buf < ft.nh) ft.halo[buf][off] = 0;
        return;
    }
    int row = idx >> 5;
    int c8  = (idx & 31) << 3;
    int m, rb, dim;
    if (row < 23104)      { m = 0; rb = 0;     dim = 38; }
    else if (row < 28880) { m = 1; rb = 23104; dim = 19; }
    else if (row < 30480) { m = 2; rb = 28880; dim = 10; }
    else if (row < 30880) { m = 3; rb = 30480; dim = 5;  }
    else if (row < 31024) { m = 4; rb = 30880; dim = 3;  }
    else                  { m = 5; rb = 31024; dim = 1;  }
    int HW = dim * dim;
    int rel = row - rb;
    int b = rel / HW;
    int hw = rel - b * HW;
    const float* s = ft.src[m] + (size_t)(b * 256 + c8) * HW + hw;
    union { unsigned short u[8]; uint4 v; } tmp;
#pragma unroll
    for (int j = 0; j < 8; ++j) tmp.u[j] = f2bf(s[(size_t)j * HW]);
    *reinterpret_cast<uint4*>(X0 + ((size_t)row << 8) + c8) = tmp.v;
}

// ---------------------------------------------------------------------------
// conv_gemm (round-13 best): 3x3 conv C256->C256 (+bias+ReLU).
// 256x256 tile, 512 thr = 8 waves (2M x 4N), 128x64 per wave.
// BK=32, 4-deep LDS ring, counted vmcnt(8), ONE barrier/step.
// ds_reads + MFMAs compiler-scheduled (fine-grained lgkmcnt).
// ---------------------------------------------------------------------------
struct GArgs {
    const unsigned short* X[2];
    const unsigned short* W[2];
    const float* B[2];
    unsigned short* Y[2];
};

__global__ __launch_bounds__(512, 2) void conv_gemm(GArgs ga) {
    __shared__ unsigned char As[65536];   // 4 slots x [256 rows][32ch] bf16
    __shared__ unsigned char Bs[65536];   // 4 slots x [256 cols][32ch]

    const int hz = blockIdx.y;
    const unsigned char* __restrict__ Xb = (const unsigned char*)ga.X[hz];
    const unsigned char* __restrict__ Wt = (const unsigned char*)ga.W[hz];
    const float* __restrict__ bias = ga.B[hz];
    unsigned short* __restrict__ Y = ga.Y[hz];

    int rb, dim, row0;
    tile256(blockIdx.x, rb, dim, row0);
    const int HWm = dim * dim;
    const int rowEnd = rb + 16 * HWm;

    const int tid = threadIdx.x;
    const int lane = tid & 63, wid = tid >> 6;
    const int lr = lane & 15, lg = lane >> 4;
    const int wm = wid >> 2, wn = wid & 3;

    // ---- staging geometry: each thread sources 16B quarters of rows sr0, sr0+128
    const int sr0 = tid >> 2;
    const int xsw = (((tid & 3) ^ ((sr0 >> 1) & 3)) << 4);   // XOR-swizzled quarter
    const unsigned char* Zr = Xb + ZOFFB + xsw;

    int gg[2], ay[2], ax[2];
    bool av[2];
#pragma unroll
    for (int it = 0; it < 2; ++it) {
        int g = row0 + sr0 + it * 128;
        bool v = g < rowEnd;
        int rel = v ? (g - rb) : 0;
        int b = rel / HWm;
        int hw = rel - b * HWm;
        int y = hw / dim;
        gg[it] = g; ay[it] = y; ax[it] = hw - y * dim; av[it] = v;
    }

    const unsigned char* bsrc0 = Wt + (size_t)sr0 * 4608 + xsw;
    const unsigned char* bsrc1 = Wt + (size_t)(sr0 + 128) * 4608 + xsw;

    auto tapA = [&](int tap, const unsigned char*& p0, const unsigned char*& p1) {
        int q3 = tap / 3;
        int dy = q3 - 1, dx = tap - q3 * 3 - 1;
        int ddd = dy * dim + dx;
        bool v0 = av[0] && ((unsigned)(ay[0] + dy) < (unsigned)dim) && ((unsigned)(ax[0] + dx) < (unsigned)dim);
        bool v1 = av[1] && ((unsigned)(ay[1] + dy) < (unsigned)dim) && ((unsigned)(ax[1] + dx) < (unsigned)dim);
        p0 = v0 ? Xb + (size_t)(gg[0] + ddd) * 512 + xsw : Zr;
        p1 = v1 ? Xb + (size_t)(gg[1] + ddd) * 512 + xsw : Zr;
    };

    // ---- fragment read offsets (swizzle folds to lr-only term)
    const int fswz = ((lg ^ ((lr >> 1) & 3)) << 4);
    const int aRd = (wm * 128 + lr) * 64 + fswz;
    const int bRd = (wn * 64 + lr) * 64 + fswz;
    const int dSt = wid * 1024;

    f32x4 acc[8][4];
#pragma unroll
    for (int i = 0; i < 8; ++i)
#pragma unroll
        for (int j = 0; j < 4; ++j) acc[i][j] = (f32x4){0.f, 0.f, 0.f, 0.f};

    // ---- prologue: stage K-tiles 0,1,2 (tap 0)
    const unsigned char *aC0, *aC1, *aN0, *aN1;
    tapA(0, aC0, aC1);
#pragma unroll
    for (int kt = 0; kt < 3; ++kt) {
        gload16(aC0 + kt * 64, As + kt * 16384 + dSt);
        gload16(aC1 + kt * 64, As + kt * 16384 + 8192 + dSt);
        gload16(bsrc0 + kt * 64, Bs + kt * 16384 + dSt);
        gload16(bsrc1 + kt * 64, Bs + kt * 16384 + 8192 + dSt);
    }

    // ---- main loop: 9 taps x 8 K-tiles of 32 channels (t = tap*8+kc)
#pragma unroll 1
    for (int tap = 0; tap < 9; ++tap) {
        if (tap < 8) tapA(tap + 1, aN0, aN1);
        else { aN0 = Zr; aN1 = Zr; }
        const unsigned char* bT0 = bsrc0 + tap * 512;
        const unsigned char* bT1 = bsrc1 + tap * 512;

#pragma unroll
        for (int kc = 0; kc < 8; ++kc) {
            const int bufc = kc & 3;          // slot holding K-tile t
            const int bufs = (kc + 3) & 3;    // slot being staged (t+3)

            // counted cross-wave sync: stage(t-3) (writers of slot bufc) complete
            asm volatile("s_waitcnt vmcnt(8)" ::: "memory");
            __builtin_amdgcn_s_barrier();
            asm volatile("" ::: "memory");    // no memory op crosses the barrier

            // stage K-tile t+3
            {
                const unsigned char *sa0, *sa1, *sb0, *sb1;
                if (kc < 5) {
                    sa0 = aC0 + (kc + 3) * 64; sa1 = aC1 + (kc + 3) * 64;
                    sb0 = bT0 + (kc + 3) * 64; sb1 = bT1 + (kc + 3) * 64;
                } else {
                    sa0 = aN0 + (kc - 5) * 64; sa1 = aN1 + (kc - 5) * 64;
                    sb0 = bT0 + 512 + (kc - 5) * 64; sb1 = bT1 + 512 + (kc - 5) * 64;
                }
                gload16(sa0, As + bufs * 16384 + dSt);
                gload16(sa1, As + bufs * 16384 + 8192 + dSt);
                gload16(sb0, Bs + bufs * 16384 + dSt);
                gload16(sb1, Bs + bufs * 16384 + 8192 + dSt);
            }

            // fragments + MFMA: compiler-scheduled (fine-grained lgkmcnt)
            const unsigned char* ab = As + bufc * 16384;
            const unsigned char* bb = Bs + bufc * 16384;
            bf16x8 rA[8], rB[4];
#pragma unroll
            for (int j = 0; j < 4; ++j) rB[j] = *(const bf16x8*)(bb + bRd + j * 1024);
#pragma unroll
            for (int i = 0; i < 8; ++i) rA[i] = *(const bf16x8*)(ab + aRd + i * 1024);
#pragma unroll
            for (int i = 0; i < 8; ++i)
#pragma unroll
                for (int j = 0; j < 4; ++j)
                    acc[i][j] = __builtin_amdgcn_mfma_f32_16x16x32_bf16(rA[i], rB[j], acc[i][j], 0, 0, 0);
        }
        aC0 = aN0; aC1 = aN1;
    }

    // ---- epilogue: bias + ReLU + bf16 store
    float bj[4];
#pragma unroll
    for (int j = 0; j < 4; ++j) bj[j] = bias[wn * 64 + j * 16 + lr];
#pragma unroll
    for (int i = 0; i < 8; ++i) {
        int rbase = row0 + wm * 128 + i * 16 + lg * 4;
#pragma unroll
        for (int rr = 0; rr < 4; ++rr) {
            int orow = rbase + rr;
            if (orow < rowEnd) {
                size_t yb = (size_t)orow * 256 + wn * 64 + lr;
#pragma unroll
                for (int j = 0; j < 4; ++j) {
                    float v = acc[i][j][rr] + bj[j];
                    Y[yb + j * 16] = f2bf(fmaxf(v, 0.f));
                }
            }
        }
    }
}

// ---------------------------------------------------------------------------
// conv_final: last conv (Cout pad 64) + bias + anchor-layout scatter, both heads.
// 128x64 tile, 4 waves stacked in M (32x64 each). Ring-4, counted vmcnt(6),
// one barrier/step, compiler-scheduled.
// ---------------------------------------------------------------------------
struct FArgs {
    const unsigned short* X[2];
    const unsigned short* W[2];
    const float* B[2];
    float* out;
    int hbase;
};

__global__ __launch_bounds__(256) void conv_final(FArgs fa) {
    __shared__ unsigned char As[32768];   // 4 slots x 8KB: [128 rows][64B]
    __shared__ unsigned char Bs[16384];   // 4 slots x 4KB: [64 cols][64B]

    const int zi = blockIdx.z;
    const int hz = zi + fa.hbase;
    const unsigned char* Xb = (const unsigned char*)fa.X[zi];
    const unsigned char* Wt = (const unsigned char*)fa.W[zi];
    const float* bias = fa.B[zi];
    float* out = fa.out;

    int rb, dim, row0, aoff;
    tile128(blockIdx.x, rb, dim, row0, aoff);
    const int HWm = dim * dim;
    const int rowEnd = rb + 16 * HWm;

    const int tid = threadIdx.x;
    const int lane = tid & 63, wid = tid >> 6;
    const int lr = lane & 15, lg = lane >> 4;

    const int swz16 = (((lane & 3) ^ ((lane >> 3) & 3)) << 4);
    const int srow = wid * 16 + (lane >> 2);
    const unsigned char* Zr = Xb + ZOFFB + swz16;

    int ay[2], ax[2], arel[2];
    bool av0[2];
#pragma unroll
    for (int it = 0; it < 2; ++it) {
        int r = row0 + it * 64 + srow;
        bool v = r < rowEnd;
        int rel = v ? (r - rb) : 0;
        int b = rel / HWm;
        int hw = rel - b * HWm;
        int y = hw / dim;
        ay[it] = y; ax[it] = hw - y * dim; arel[it] = rel; av0[it] = v;
    }

    const unsigned char* bB = Wt + (size_t)srow * 4608 + swz16;

    const int fsw = ((lg ^ ((lr >> 1) & 3)) << 4);
    const int aRd = (wid * 32 + lr) * 64 + fsw;   // + i*1024 + slot*8192
    const int bRd = lr * 64 + fsw;                // + j*1024 + slot*4096
    const int dA0 = wid * 1024;

    f32x4 acc[2][4];
#pragma unroll
    for (int i = 0; i < 2; ++i)
#pragma unroll
        for (int j = 0; j < 4; ++j) acc[i][j] = (f32x4){0.f, 0.f, 0.f, 0.f};

    auto tapPtr = [&](int tap, const unsigned char** aP) {
        int q3 = tap / 3;
        int dy = q3 - 1, dx = tap - q3 * 3 - 1;
#pragma unroll
        for (int it = 0; it < 2; ++it) {
            bool v = av0[it] && ((unsigned)(ay[it] + dy) < (unsigned)dim)
                             && ((unsigned)(ax[it] + dx) < (unsigned)dim);
            int off = v ? (rb + arel[it] + dy * dim + dx) * 512 : ZOFFB;
            aP[it] = Xb + off + swz16;
        }
    };

    // ---- prologue: stage K-tiles 0,1,2 (tap 0)
    const unsigned char* aP[2];
    const unsigned char* aPn[2];
    tapPtr(0, aP);
#pragma unroll
    for (int kt = 0; kt < 3; ++kt) {
        gload16(aP[0] + kt * 64, As + kt * 8192 + dA0);
        gload16(aP[1] + kt * 64, As + kt * 8192 + 4096 + dA0);
        gload16(bB + kt * 64, Bs + kt * 4096 + dA0);
    }

    // ---- main loop: 9 taps x 8 K-tiles of 32 channels (t = tap*8+kin)
#pragma unroll 1
    for (int tap = 0; tap < 9; ++tap) {
        if (tap < 8) tapPtr(tap + 1, aPn);
        else { aPn[0] = Zr; aPn[1] = Zr; }
        const unsigned char* bP = bB + tap * 512;

#pragma unroll
        for (int kin = 0; kin < 8; ++kin) {
            const int sc = kin & 3;           // slot holding K-tile t
            const int ss = (kin + 3) & 3;     // slot being staged (t+3)

            asm volatile("s_waitcnt vmcnt(6)" ::: "memory");   // slot sc landed
            __builtin_amdgcn_s_barrier();
            asm volatile("" ::: "memory");

            // stage K-tile t+3 (dummy Zr loads past the end keep the count uniform)
            {
                const unsigned char *sa0, *sa1, *sb;
                if (tap == 8 && kin >= 5) { sa0 = Zr; sa1 = Zr; sb = Zr; }
                else if (kin < 5) {
                    sa0 = aP[0] + (kin + 3) * 64; sa1 = aP[1] + (kin + 3) * 64;
                    sb = bP + (kin + 3) * 64;
                } else {
                    sa0 = aPn[0] + (kin - 5) * 64; sa1 = aPn[1] + (kin - 5) * 64;
                    sb = bP + 512 + (kin - 5) * 64;
                }
                gload16(sa0, As + ss * 8192 + dA0);
                gload16(sa1, As + ss * 8192 + 4096 + dA0);
                gload16(sb, Bs + ss * 4096 + dA0);
            }

            // fragments + MFMA: compiler-scheduled
            const unsigned char* ab = As + sc * 8192;
            const unsigned char* bb = Bs + sc * 4096;
            bf16x8 af[2], bg[4];
#pragma unroll
            for (int j = 0; j < 4; ++j) bg[j] = *(const bf16x8*)(bb + bRd + j * 1024);
#pragma unroll
            for (int i = 0; i < 2; ++i) af[i] = *(const bf16x8*)(ab + aRd + i * 1024);
#pragma unroll
            for (int i = 0; i < 2; ++i)
#pragma unroll
                for (int j = 0; j < 4; ++j)
                    acc[i][j] = __builtin_amdgcn_mfma_f32_16x16x32_bf16(af[i], bg[j], acc[i][j], 0, 0, 0);
        }
        aP[0] = aPn[0]; aP[1] = aPn[1];
    }

    const int Cout = hz ? 54 : 24;
#pragma unroll
    for (int i = 0; i < 2; ++i) {
        int rbase = row0 + wid * 32 + i * 16 + lg * 4;
#pragma unroll
        for (int r = 0; r < 4; ++r) {
            int orow = rbase + r;
            if (orow < rowEnd) {
                int rel = orow - rb;
                int b = rel / HWm;
                int hw = rel - b * HWm;
#pragma unroll
                for (int j = 0; j < 4; ++j) {
                    int oc = j * 16 + lr;
                    if (oc < Cout) {
                        int q = oc / 6;
                        int s = oc - q * 6;
                        int anchor = aoff + s * HWm + hw;
                        float v = acc[i][j][r] + bias[oc];
                        if (hz)
                            out[744960 + (size_t)b * 104760 + (size_t)q * 11640 + anchor] = v;
                        else
                            out[(size_t)b * 46560 + (size_t)q * 11640 + anchor] = v;
                    }
                }
            }
        }
    }
}

// ---------------------------------------------------------------------------
extern "C" void kernel_launch(void* const* d_in, const int* in_sizes, int n_in,
                              void* d_out, int out_size, void* d_ws, size_t ws_size,
                              hipStream_t stream) {
    (void)in_sizes; (void)n_in; (void)out_size;

    const float* rw[5]  = {(const float*)d_in[6],  (const float*)d_in[8],
                           (const float*)d_in[10], (const float*)d_in[12],
                           (const float*)d_in[14]};
    const float* rbv[5] = {(const float*)d_in[7],  (const float*)d_in[9],
                           (const float*)d_in[11], (const float*)d_in[13],
                           (const float*)d_in[15]};
    const float* cw[5]  = {(const float*)d_in[16], (const float*)d_in[18],
                           (const float*)d_in[20], (const float*)d_in[22],
                           (const float*)d_in[24]};
    const float* cbv[5] = {(const float*)d_in[17], (const float*)d_in[19],
                           (const float*)d_in[21], (const float*)d_in[23],
                           (const float*)d_in[25]};

    const size_t ACTB = 31041ull * 512;
    const size_t WMAT = 589824;
    const size_t WBYTES = 8 * WMAT * 2;
    const size_t WFBYTES = 2 * 147456 * 2;
    const size_t needF = 4 * ACTB + WBYTES + WFBYTES;
    const size_t needS = 3 * ACTB + WBYTES + WFBYTES;

    unsigned char* ws = (unsigned char*)d_ws;
    bool fused = (ws_size >= needF);
    if (!fused && ws_size < needS) return;

    int nact = fused ? 4 : 3;
    unsigned short* act[4];
    for (int i = 0; i < nact; ++i) act[i] = (unsigned short*)(ws + (size_t)i * ACTB);
    unsigned short* Wb = (unsigned short*)(ws + (size_t)nact * ACTB);
    unsigned short* WF = (unsigned short*)(ws + (size_t)nact * ACTB + WBYTES);

    WT wt;
    for (int l = 0; l < 4; ++l) { wt.src[l] = rw[l]; wt.src[4 + l] = cw[l]; }
    wt.src[8] = rw[4]; wt.src[9] = cw[4];
    wtrans_all<<<2176, 256, 0, stream>>>(wt, Wb, WF);

    FT ft;
    for (int i = 0; i < 6; ++i) ft.src[i] = (const float*)d_in[i];
    for (int i = 0; i < 4; ++i)
        ft.halo[i] = (unsigned short*)((unsigned char*)act[i < nact ? i : 0] + ZOFFB);
    ft.nh = nact;
    ftrans_all<<<3884, 256, 0, stream>>>(ft, act[0]);

    const unsigned short* Wr[5], *Wc[5];
    for (int l = 0; l < 4; ++l) {
        Wr[l] = Wb + (size_t)l * WMAT;
        Wc[l] = Wb + (size_t)(4 + l) * WMAT;
    }
    Wr[4] = WF; Wc[4] = WF + 147456;

    if (fused) {
        unsigned short* X0 = act[0];
        unsigned short* P = act[1];
        unsigned short* Q = act[2];
        unsigned short* R = act[3];
        GArgs l1 = {{X0, X0}, {Wr[0], Wc[0]}, {rbv[0], cbv[0]}, {P, Q}};
        GArgs l2 = {{P,  Q},  {Wr[1], Wc[1]}, {rbv[1], cbv[1]}, {X0, R}};
        GArgs l3 = {{X0, R},  {Wr[2], Wc[2]}, {rbv[2], cbv[2]}, {P, Q}};
        GArgs l4 = {{P,  Q},  {Wr[3], Wc[3]}, {rbv[3], cbv[3]}, {X0, R}};
        conv_gemm<<<dim3(125, 2), 512, 0, stream>>>(l1);
        conv_gemm<<<dim3(125, 2), 512, 0, stream>>>(l2);
        conv_gemm<<<dim3(125, 2), 512, 0, stream>>>(l3);
        conv_gemm<<<dim3(125, 2), 512, 0, stream>>>(l4);
        FArgs lf = {{X0, R}, {Wr[4], Wc[4]}, {rbv[4], cbv[4]}, (float*)d_out, 0};
        conv_final<<<dim3(247, 1, 2), 256, 0, stream>>>(lf);
    } else {
        unsigned short* X0 = act[0];
        unsigned short* A1 = act[1];
        unsigned short* A2 = act[2];
        for (int h = 0; h < 2; ++h) {
            const unsigned short* const* W = h ? Wc : Wr;
            const float* const* bs = h ? cbv : rbv;
            GArgs l1 = {{X0, X0}, {W[0], W[0]}, {bs[0], bs[0]}, {A1, A1}};
            GArgs l2 = {{A1, A1}, {W[1], W[1]}, {bs[1], bs[1]}, {A2, A2}};
            GArgs l3 = {{A2, A2}, {W[2], W[2]}, {bs[2], bs[2]}, {A1, A1}};
            GArgs l4 = {{A1, A1}, {W[3], W[3]}, {bs[3], bs[3]}, {A2, A2}};
            conv_gemm<<<dim3(125, 1), 512, 0, stream>>>(l1);
            conv_gemm<<<dim3(125, 1), 512, 0, stream>>>(l2);
            conv_gemm<<<dim3(125, 1), 512, 0, stream>>>(l3);
            conv_gemm<<<dim3(125, 1), 512, 0, stream>>>(l4);
            FArgs lf = {{A2, A2}, {W[4], W[4]}, {bs[4], bs[4]}, (float*)d_out, h};
            conv_final<<<dim3(247, 1, 1), 256, 0, stream>>>(lf);
        }
    }
}